// Round 4
// baseline (591.212 us; speedup 1.0000x reference)
//
#include <hip/hip_runtime.h>

// Problem constants (from reference)
#define FDIM 512
#define TDK  0.1f   // TIME_DECAY
#define DTs  0.2f   // DIFF_T / NUM_STEPS
#define EPSv 1e-5f

using bf16x8  = __attribute__((ext_vector_type(8))) __bf16;
using floatx4 = __attribute__((ext_vector_type(4))) float;
using ushort8 = __attribute__((ext_vector_type(8))) unsigned short;

__device__ __forceinline__ unsigned short f2bf(float f) {
  unsigned int u = __float_as_uint(f);
  u += 0x7fffu + ((u >> 16) & 1u);   // RNE
  return (unsigned short)(u >> 16);
}

// ---------------- ts.max() over timestamps (graph_time folded in later) -------
__global__ __launch_bounds__(256) void tsmax_kernel(const float* __restrict__ ts, int E,
                                                    float* __restrict__ out) {
  float m = 0.f;  // timestamps >= 0
  for (int i = blockIdx.x * blockDim.x + threadIdx.x; i < E; i += gridDim.x * blockDim.x)
    m = fmaxf(m, ts[i]);
  for (int off = 32; off; off >>= 1) m = fmaxf(m, __shfl_down(m, off));
  __shared__ float sm[4];
  int wid = threadIdx.x >> 6, lane = threadIdx.x & 63;
  if (lane == 0) sm[wid] = m;
  __syncthreads();
  if (threadIdx.x == 0) {
    float mm = fmaxf(fmaxf(sm[0], sm[1]), fmaxf(sm[2], sm[3]));
    atomicMax((int*)out, __float_as_int(mm));  // positive floats: int order == float order
  }
}

// -------- per-edge decay weight + weighted degree (dst) + CSR row counts ------
__global__ __launch_bounds__(256) void edge_w_deg(const int* __restrict__ src, const int* __restrict__ dst,
                                                  const float* __restrict__ ts, const float* __restrict__ tsmax_p,
                                                  const int* __restrict__ gt_p,
                                                  float* __restrict__ w, float* __restrict__ deg,
                                                  int* __restrict__ cnt, int E, int N) {
  int e = blockIdx.x * blockDim.x + threadIdx.x;
  int total = E + N;
  if (e >= total) return;
  float gtf = (float)(*gt_p);
  float tm = fmaxf(*tsmax_p, gtf);
  int d; float t;
  if (e < E) { d = dst[e]; t = ts[e]; }
  else       { d = e - E;  t = gtf; }
  float wv = expf(-TDK * (tm - t));
  w[e] = wv;
  atomicAdd(&deg[d], wv);
  atomicAdd(&cnt[d], 1);
}

__global__ __launch_bounds__(256) void dinv_kernel(const float* __restrict__ deg, float* __restrict__ dinv, int N) {
  int i = blockIdx.x * blockDim.x + threadIdx.x;
  if (i >= N) return;
  float d = deg[i];
  dinv[i] = (d > 0.f) ? rsqrtf(d) : 0.f;
}

// ---------------- single-block exclusive scan for CSR offsets -----------------
__global__ __launch_bounds__(256) void scan_offsets(const int* __restrict__ cnt, int* __restrict__ offs,
                                                    int* __restrict__ cursor, int n) {
  __shared__ int sums[256];
  int tid = threadIdx.x;
  int chunk = (n + 255) >> 8;
  int start = tid * chunk;
  int end = min(start + chunk, n);
  int s = 0;
  for (int i = start; i < end; ++i) s += cnt[i];
  sums[tid] = s;
  __syncthreads();
  for (int off = 1; off < 256; off <<= 1) {
    int v = (tid >= off) ? sums[tid - off] : 0;
    __syncthreads();
    sums[tid] += v;
    __syncthreads();
  }
  int prefix = (tid == 0) ? 0 : sums[tid - 1];
  for (int i = start; i < end; ++i) {
    offs[i] = prefix; cursor[i] = prefix; prefix += cnt[i];
  }
  if (tid == 255) offs[n] = prefix;
}

// -------- scatter edges into CSR (col=src, val = dinv[src]*w*dinv[dst]) -------
__global__ __launch_bounds__(256) void scatter_kernel(const int* __restrict__ src, const int* __restrict__ dst,
                                                      const float* __restrict__ w, const float* __restrict__ dinv,
                                                      int* __restrict__ cursor, int* __restrict__ col,
                                                      float* __restrict__ val, int E, int N) {
  int e = blockIdx.x * blockDim.x + threadIdx.x;
  if (e >= E + N) return;
  int s, d;
  if (e < E) { s = src[e]; d = dst[e]; }
  else       { s = d = e - E; }
  int pos = atomicAdd(&cursor[d], 1);
  col[pos] = s;
  val[pos] = dinv[s] * w[e] * dinv[d];
}

// ------------- one diffusion step, bf16 state: h_out = (1-dt)h_in + dt*(A h_in)
// ONE WAVE PER ROW: 64 lanes x 16 B (bf16x8) = the full 1 KB feature row.
// Edge loop unrolled x8 (8 independent dwordx4 gathers in flight per wave).
__device__ __forceinline__ void acc8(uint4 u, float v, float* a) {
  a[0] += v * __uint_as_float(u.x << 16);
  a[1] += v * __uint_as_float(u.x & 0xffff0000u);
  a[2] += v * __uint_as_float(u.y << 16);
  a[3] += v * __uint_as_float(u.y & 0xffff0000u);
  a[4] += v * __uint_as_float(u.z << 16);
  a[5] += v * __uint_as_float(u.z & 0xffff0000u);
  a[6] += v * __uint_as_float(u.w << 16);
  a[7] += v * __uint_as_float(u.w & 0xffff0000u);
}

__global__ __launch_bounds__(256) void spmm_step_bf16(const int* __restrict__ offs, const int* __restrict__ col,
                                                      const float* __restrict__ val,
                                                      const unsigned short* __restrict__ h_in,
                                                      unsigned short* __restrict__ h_out, int N) {
  int row = blockIdx.x * 4 + (threadIdx.x >> 6);
  if (row >= N) return;
  int lane = threadIdx.x & 63;
  int fo = lane * 8;  // 8 bf16 = 16 B per lane
  int s = offs[row], e = offs[row + 1];
  float a[8] = {0.f, 0.f, 0.f, 0.f, 0.f, 0.f, 0.f, 0.f};
  int j = s;
  for (; j + 8 <= e; j += 8) {
    int c[8]; float v[8]; uint4 u[8];
#pragma unroll
    for (int t = 0; t < 8; ++t) { c[t] = col[j + t]; v[t] = val[j + t]; }
#pragma unroll
    for (int t = 0; t < 8; ++t) u[t] = *(const uint4*)(h_in + (size_t)c[t] * FDIM + fo);
#pragma unroll
    for (int t = 0; t < 8; ++t) acc8(u[t], v[t], a);
  }
  if (j + 4 <= e) {
    int c[4]; float v[4]; uint4 u[4];
#pragma unroll
    for (int t = 0; t < 4; ++t) { c[t] = col[j + t]; v[t] = val[j + t]; }
#pragma unroll
    for (int t = 0; t < 4; ++t) u[t] = *(const uint4*)(h_in + (size_t)c[t] * FDIM + fo);
#pragma unroll
    for (int t = 0; t < 4; ++t) acc8(u[t], v[t], a);
    j += 4;
  }
  for (; j < e; ++j) {
    int c = col[j];
    float v = val[j];
    uint4 u = *(const uint4*)(h_in + (size_t)c * FDIM + fo);
    acc8(u, v, a);
  }
  // self term: h + dt*(Ah - h)
  uint4 ud = *(const uint4*)(h_in + (size_t)row * FDIM + fo);
  float hd[8];
  hd[0] = __uint_as_float(ud.x << 16); hd[1] = __uint_as_float(ud.x & 0xffff0000u);
  hd[2] = __uint_as_float(ud.y << 16); hd[3] = __uint_as_float(ud.y & 0xffff0000u);
  hd[4] = __uint_as_float(ud.z << 16); hd[5] = __uint_as_float(ud.z & 0xffff0000u);
  hd[6] = __uint_as_float(ud.w << 16); hd[7] = __uint_as_float(ud.w & 0xffff0000u);
  uint4 o;
  unsigned int p0, p1;
#define PACK(k0, k1, dst_)                                        \
  { float o0 = hd[k0] + DTs * (a[k0] - hd[k0]);                   \
    float o1 = hd[k1] + DTs * (a[k1] - hd[k1]);                   \
    p0 = f2bf(o0); p1 = f2bf(o1); dst_ = p0 | (p1 << 16); }
  PACK(0, 1, o.x) PACK(2, 3, o.y) PACK(4, 5, o.z) PACK(6, 7, o.w)
#undef PACK
  *(uint4*)(h_out + (size_t)row * FDIM + fo) = o;
}

// ------------------------------ fp32 -> bf16 cast -----------------------------
__global__ __launch_bounds__(256) void cast_bf16(const float* __restrict__ srcp,
                                                 unsigned short* __restrict__ dstp, int n8) {
  int i = blockIdx.x * blockDim.x + threadIdx.x;
  if (i >= n8) return;
  const float4 v0 = *(const float4*)(srcp + (size_t)i * 8);
  const float4 v1 = *(const float4*)(srcp + (size_t)i * 8 + 4);
  ushort8 o;
  o[0] = f2bf(v0.x); o[1] = f2bf(v0.y); o[2] = f2bf(v0.z); o[3] = f2bf(v0.w);
  o[4] = f2bf(v1.x); o[5] = f2bf(v1.y); o[6] = f2bf(v1.z); o[7] = f2bf(v1.w);
  *(ushort8*)(dstp + (size_t)i * 8) = o;
}

// ---------------- fused dual GEMM, direct-from-global (no LDS) ----------------
// out = relu(Ah @ Wt^T + bias) + Ax @ Wr^T
// Both operands are [rows][K] with K contiguous; the 16x16x32 MFMA fragment is
// exactly 8 contiguous K elems (16 B) per lane, so fragments load straight from
// global: each frag load = 16 fully-used 64 B lines. No LDS, no barriers, no
// bank conflicts. Tile 128x128 per block (4 waves 2x2), each byte read once
// per block (same traffic as LDS staging would have).
__global__ __launch_bounds__(256) void gemm_fused(const __bf16* __restrict__ Ah, const __bf16* __restrict__ Ax,
                                                  const __bf16* __restrict__ Wt, const __bf16* __restrict__ Wr,
                                                  const float* __restrict__ bias, float* __restrict__ out,
                                                  int M) {
  int tid = threadIdx.x;
  int wid = tid >> 6, lane = tid & 63;
  int wm = wid & 1, wn = wid >> 1;
  int lane15 = lane & 15, quad = lane >> 4;
  int m0 = blockIdx.x * 128, n0 = blockIdx.y * 128;

  // per-lane element offsets (shared between the two A mats / two B mats)
  int aoff[4], boff[4];
  float bn[4];
#pragma unroll
  for (int im = 0; im < 4; ++im) {
    int m = m0 + wm * 64 + im * 16 + lane15;
    if (m >= M) m = M - 1;
    aoff[im] = m * FDIM + quad * 8;
  }
#pragma unroll
  for (int in = 0; in < 4; ++in) {
    int n = n0 + wn * 64 + in * 16 + lane15;
    boff[in] = n * FDIM + quad * 8;
    bn[in] = bias[n];
  }

  floatx4 acc1[4][4], acc2[4][4];
  floatx4 z4; z4[0] = 0.f; z4[1] = 0.f; z4[2] = 0.f; z4[3] = 0.f;
#pragma unroll
  for (int im = 0; im < 4; ++im)
#pragma unroll
    for (int in = 0; in < 4; ++in) { acc1[im][in] = z4; acc2[im][in] = z4; }

  for (int k = 0; k < FDIM; k += 32) {
    bf16x8 a1[4], b1[4], a2[4], b2[4];
#pragma unroll
    for (int im = 0; im < 4; ++im) a1[im] = *(const bf16x8*)(Ah + aoff[im] + k);
#pragma unroll
    for (int in = 0; in < 4; ++in) b1[in] = *(const bf16x8*)(Wt + boff[in] + k);
#pragma unroll
    for (int im = 0; im < 4; ++im) a2[im] = *(const bf16x8*)(Ax + aoff[im] + k);
#pragma unroll
    for (int in = 0; in < 4; ++in) b2[in] = *(const bf16x8*)(Wr + boff[in] + k);
#pragma unroll
    for (int im = 0; im < 4; ++im)
#pragma unroll
      for (int in = 0; in < 4; ++in)
        acc1[im][in] = __builtin_amdgcn_mfma_f32_16x16x32_bf16(a1[im], b1[in], acc1[im][in], 0, 0, 0);
#pragma unroll
    for (int im = 0; im < 4; ++im)
#pragma unroll
      for (int in = 0; in < 4; ++in)
        acc2[im][in] = __builtin_amdgcn_mfma_f32_16x16x32_bf16(a2[im], b2[in], acc2[im][in], 0, 0, 0);
  }

  // epilogue: C/D layout col=lane&15, row=quad*4+reg
#pragma unroll
  for (int im = 0; im < 4; ++im) {
#pragma unroll
    for (int in = 0; in < 4; ++in) {
#pragma unroll
      for (int r = 0; r < 4; ++r) {
        int m = m0 + wm * 64 + im * 16 + quad * 4 + r;
        int n = n0 + wn * 64 + in * 16 + lane15;
        if (m < M) {
          float v = fmaxf(acc1[im][in][r] + bn[in], 0.f) + acc2[im][in][r];
          out[(size_t)m * FDIM + n] = v;
        }
      }
    }
  }
}

// ------------------------------ rowwise LayerNorm -----------------------------
__global__ __launch_bounds__(256) void ln_kernel(const float* __restrict__ pre, const float* __restrict__ gamma,
                                                 const float* __restrict__ beta, float* __restrict__ out) {
  int row = blockIdx.x, t = threadIdx.x;
  float2 v = *(const float2*)(pre + (size_t)row * FDIM + t * 2);
  float s = v.x + v.y;
  float ss = v.x * v.x + v.y * v.y;
  for (int off = 32; off; off >>= 1) { s += __shfl_down(s, off); ss += __shfl_down(ss, off); }
  __shared__ float sm[4], sm2[4];
  int wid = t >> 6, lane = t & 63;
  if (lane == 0) { sm[wid] = s; sm2[wid] = ss; }
  __syncthreads();
  if (t == 0) {
    float a = sm[0] + sm[1] + sm[2] + sm[3];
    float b = sm2[0] + sm2[1] + sm2[2] + sm2[3];
    sm[0] = a; sm2[0] = b;
  }
  __syncthreads();
  float mu = sm[0] * (1.f / FDIM);
  float var = sm2[0] * (1.f / FDIM) - mu * mu;
  float inv = rsqrtf(var + EPSv);
  float2 g  = *(const float2*)(gamma + t * 2);
  float2 bb = *(const float2*)(beta + t * 2);
  float2 o;
  o.x = (v.x - mu) * inv * g.x + bb.x;
  o.y = (v.y - mu) * inv * g.y + bb.y;
  *(float2*)(out + (size_t)row * FDIM + t * 2) = o;
}

extern "C" void kernel_launch(void* const* d_in, const int* in_sizes, int n_in,
                              void* d_out, int out_size, void* d_ws, size_t ws_size,
                              hipStream_t stream) {
  const float* x     = (const float*)d_in[0];
  const int*   ei    = (const int*)d_in[1];
  const float* ts    = (const float*)d_in[2];
  const float* W_t   = (const float*)d_in[3];
  const float* b_t   = (const float*)d_in[4];
  const float* W_r   = (const float*)d_in[5];
  const float* gamma = (const float*)d_in[6];
  const float* beta  = (const float*)d_in[7];
  const int*   gt    = (const int*)d_in[8];

  const int E = in_sizes[2];
  const int N = in_sizes[0] / FDIM;
  const int* src = ei;
  const int* dst = ei + E;
  const int totE = E + N;

  // ---- workspace carve (all regions fully rewritten every call) ----
  char* base = (char*)d_ws;
  size_t off = 0;
  auto carve = [&](size_t bytes) -> char* {
    char* r = base + off;
    off = (off + bytes + 255) & ~(size_t)255;
    return r;
  };
  float* tsmax = (float*)carve(4);
  float* deg   = (float*)carve((size_t)N * 4);
  int*   cnt   = (int*)  carve((size_t)N * 4);
  size_t zero_bytes = off;                       // tsmax+deg+cnt need zeroing
  float* dinv  = (float*)carve((size_t)N * 4);
  int*   offs  = (int*)  carve((size_t)(N + 1) * 4);
  int*   cursor= (int*)  carve((size_t)N * 4);
  float* w     = (float*)carve((size_t)totE * 4);
  int*   col   = (int*)  carve((size_t)totE * 4);
  float* val   = (float*)carve((size_t)totE * 4);
  unsigned short* xb  = (unsigned short*)carve((size_t)N * FDIM * 2);   // bf16(x)
  unsigned short* hba = (unsigned short*)carve((size_t)N * FDIM * 2);   // bf16 h ping
  unsigned short* hbb = (unsigned short*)carve((size_t)N * FDIM * 2);   // bf16 h pong
  unsigned short* wtb = (unsigned short*)carve((size_t)FDIM * FDIM * 2);
  unsigned short* wrb = (unsigned short*)carve((size_t)FDIM * FDIM * 2);
  float* preLN = (float*)carve((size_t)N * FDIM * 4);

  hipMemsetAsync(d_ws, 0, zero_bytes, stream);

  tsmax_kernel<<<64, 256, 0, stream>>>(ts, E, tsmax);
  edge_w_deg<<<(totE + 255) / 256, 256, 0, stream>>>(src, dst, ts, tsmax, gt, w, deg, cnt, E, N);
  dinv_kernel<<<(N + 255) / 256, 256, 0, stream>>>(deg, dinv, N);
  scan_offsets<<<1, 256, 0, stream>>>(cnt, offs, cursor, N);
  scatter_kernel<<<(totE + 255) / 256, 256, 0, stream>>>(src, dst, w, dinv, cursor, col, val, E, N);

  // casts to bf16 (x and weights; x feeds both the diffusion and the residual GEMM)
  int n8x = N * FDIM / 8;
  cast_bf16<<<(n8x + 255) / 256, 256, 0, stream>>>(x, xb, n8x);
  int n8w = FDIM * FDIM / 8;
  cast_bf16<<<(n8w + 255) / 256, 256, 0, stream>>>(W_t, wtb, n8w);
  cast_bf16<<<(n8w + 255) / 256, 256, 0, stream>>>(W_r, wrb, n8w);

  // 5 Euler steps on bf16 state: xb -> hba -> hbb -> hba -> hbb -> hba
  int sg = (N + 3) / 4;
  spmm_step_bf16<<<sg, 256, 0, stream>>>(offs, col, val, xb,  hba, N);
  spmm_step_bf16<<<sg, 256, 0, stream>>>(offs, col, val, hba, hbb, N);
  spmm_step_bf16<<<sg, 256, 0, stream>>>(offs, col, val, hbb, hba, N);
  spmm_step_bf16<<<sg, 256, 0, stream>>>(offs, col, val, hba, hbb, N);
  spmm_step_bf16<<<sg, 256, 0, stream>>>(offs, col, val, hbb, hba, N);

  // fused: preLN = relu(h @ Wt^T + b_t) + x @ Wr^T
  dim3 gg((N + 127) / 128, FDIM / 128);
  gemm_fused<<<gg, 256, 0, stream>>>((const __bf16*)hba, (const __bf16*)xb,
                                     (const __bf16*)wtb, (const __bf16*)wrb,
                                     b_t, preLN, N);

  ln_kernel<<<N, 256, 0, stream>>>(preLN, gamma, beta, (float*)d_out);
}

// Round 5
// 517.056 us; speedup vs baseline: 1.1434x; 1.1434x over previous
//
#include <hip/hip_runtime.h>

// Problem constants (from reference)
#define FDIM 512
#define TDK  0.1f   // TIME_DECAY
#define DTs  0.2f   // DIFF_T / NUM_STEPS
#define EPSv 1e-5f

using bf16x8  = __attribute__((ext_vector_type(8))) __bf16;
using floatx4 = __attribute__((ext_vector_type(4))) float;
using ushort8 = __attribute__((ext_vector_type(8))) unsigned short;

__device__ __forceinline__ unsigned short f2bf(float f) {
  unsigned int u = __float_as_uint(f);
  u += 0x7fffu + ((u >> 16) & 1u);   // RNE
  return (unsigned short)(u >> 16);
}

// async global->LDS, 16 B per lane; LDS dest = wave-uniform base + lane*16
__device__ __forceinline__ void gld16(const __bf16* g, __bf16* l) {
  __builtin_amdgcn_global_load_lds(
      (const __attribute__((address_space(1))) unsigned int*)g,
      (__attribute__((address_space(3))) unsigned int*)l, 16, 0, 0);
}

// ---------------- ts.max() over timestamps (graph_time folded in later) -------
__global__ __launch_bounds__(256) void tsmax_kernel(const float* __restrict__ ts, int E,
                                                    float* __restrict__ out) {
  float m = 0.f;  // timestamps >= 0
  for (int i = blockIdx.x * blockDim.x + threadIdx.x; i < E; i += gridDim.x * blockDim.x)
    m = fmaxf(m, ts[i]);
  for (int off = 32; off; off >>= 1) m = fmaxf(m, __shfl_down(m, off));
  __shared__ float sm[4];
  int wid = threadIdx.x >> 6, lane = threadIdx.x & 63;
  if (lane == 0) sm[wid] = m;
  __syncthreads();
  if (threadIdx.x == 0) {
    float mm = fmaxf(fmaxf(sm[0], sm[1]), fmaxf(sm[2], sm[3]));
    atomicMax((int*)out, __float_as_int(mm));  // positive floats: int order == float order
  }
}

// -------- per-edge decay weight + weighted degree (dst) + CSR row counts ------
__global__ __launch_bounds__(256) void edge_w_deg(const int* __restrict__ src, const int* __restrict__ dst,
                                                  const float* __restrict__ ts, const float* __restrict__ tsmax_p,
                                                  const int* __restrict__ gt_p,
                                                  float* __restrict__ w, float* __restrict__ deg,
                                                  int* __restrict__ cnt, int E, int N) {
  int e = blockIdx.x * blockDim.x + threadIdx.x;
  int total = E + N;
  if (e >= total) return;
  float gtf = (float)(*gt_p);
  float tm = fmaxf(*tsmax_p, gtf);
  int d; float t;
  if (e < E) { d = dst[e]; t = ts[e]; }
  else       { d = e - E;  t = gtf; }
  float wv = expf(-TDK * (tm - t));
  w[e] = wv;
  atomicAdd(&deg[d], wv);
  atomicAdd(&cnt[d], 1);
}

__global__ __launch_bounds__(256) void dinv_kernel(const float* __restrict__ deg, float* __restrict__ dinv, int N) {
  int i = blockIdx.x * blockDim.x + threadIdx.x;
  if (i >= N) return;
  float d = deg[i];
  dinv[i] = (d > 0.f) ? rsqrtf(d) : 0.f;
}

// ---------------- single-block exclusive scan for CSR offsets -----------------
__global__ __launch_bounds__(256) void scan_offsets(const int* __restrict__ cnt, int* __restrict__ offs,
                                                    int* __restrict__ cursor, int n) {
  __shared__ int sums[256];
  int tid = threadIdx.x;
  int chunk = (n + 255) >> 8;
  int start = tid * chunk;
  int end = min(start + chunk, n);
  int s = 0;
  for (int i = start; i < end; ++i) s += cnt[i];
  sums[tid] = s;
  __syncthreads();
  for (int off = 1; off < 256; off <<= 1) {
    int v = (tid >= off) ? sums[tid - off] : 0;
    __syncthreads();
    sums[tid] += v;
    __syncthreads();
  }
  int prefix = (tid == 0) ? 0 : sums[tid - 1];
  for (int i = start; i < end; ++i) {
    offs[i] = prefix; cursor[i] = prefix; prefix += cnt[i];
  }
  if (tid == 255) offs[n] = prefix;
}

// -------- scatter edges into CSR (col=src, val = dinv[src]*w*dinv[dst]) -------
__global__ __launch_bounds__(256) void scatter_kernel(const int* __restrict__ src, const int* __restrict__ dst,
                                                      const float* __restrict__ w, const float* __restrict__ dinv,
                                                      int* __restrict__ cursor, int* __restrict__ col,
                                                      float* __restrict__ val, int E, int N) {
  int e = blockIdx.x * blockDim.x + threadIdx.x;
  if (e >= E + N) return;
  int s, d;
  if (e < E) { s = src[e]; d = dst[e]; }
  else       { s = d = e - E; }
  int pos = atomicAdd(&cursor[d], 1);
  col[pos] = s;
  val[pos] = dinv[s] * w[e] * dinv[d];
}

// ------------- one diffusion step, bf16 state: h_out = (1-dt)h_in + dt*(A h_in)
// ONE WAVE PER ROW: 64 lanes x 16 B (bf16x8) = the full 1 KB feature row.
// Edge loop unrolled x8 (8 independent dwordx4 gathers in flight per wave).
__device__ __forceinline__ void acc8(uint4 u, float v, float* a) {
  a[0] += v * __uint_as_float(u.x << 16);
  a[1] += v * __uint_as_float(u.x & 0xffff0000u);
  a[2] += v * __uint_as_float(u.y << 16);
  a[3] += v * __uint_as_float(u.y & 0xffff0000u);
  a[4] += v * __uint_as_float(u.z << 16);
  a[5] += v * __uint_as_float(u.z & 0xffff0000u);
  a[6] += v * __uint_as_float(u.w << 16);
  a[7] += v * __uint_as_float(u.w & 0xffff0000u);
}

__global__ __launch_bounds__(256) void spmm_step_bf16(const int* __restrict__ offs, const int* __restrict__ col,
                                                      const float* __restrict__ val,
                                                      const unsigned short* __restrict__ h_in,
                                                      unsigned short* __restrict__ h_out, int N) {
  int row = blockIdx.x * 4 + (threadIdx.x >> 6);
  if (row >= N) return;
  int lane = threadIdx.x & 63;
  int fo = lane * 8;  // 8 bf16 = 16 B per lane
  int s = offs[row], e = offs[row + 1];
  float a[8] = {0.f, 0.f, 0.f, 0.f, 0.f, 0.f, 0.f, 0.f};
  int j = s;
  for (; j + 8 <= e; j += 8) {
    int c[8]; float v[8]; uint4 u[8];
#pragma unroll
    for (int t = 0; t < 8; ++t) { c[t] = col[j + t]; v[t] = val[j + t]; }
#pragma unroll
    for (int t = 0; t < 8; ++t) u[t] = *(const uint4*)(h_in + (size_t)c[t] * FDIM + fo);
#pragma unroll
    for (int t = 0; t < 8; ++t) acc8(u[t], v[t], a);
  }
  if (j + 4 <= e) {
    int c[4]; float v[4]; uint4 u[4];
#pragma unroll
    for (int t = 0; t < 4; ++t) { c[t] = col[j + t]; v[t] = val[j + t]; }
#pragma unroll
    for (int t = 0; t < 4; ++t) u[t] = *(const uint4*)(h_in + (size_t)c[t] * FDIM + fo);
#pragma unroll
    for (int t = 0; t < 4; ++t) acc8(u[t], v[t], a);
    j += 4;
  }
  for (; j < e; ++j) {
    int c = col[j];
    float v = val[j];
    uint4 u = *(const uint4*)(h_in + (size_t)c * FDIM + fo);
    acc8(u, v, a);
  }
  // self term: h + dt*(Ah - h)
  uint4 ud = *(const uint4*)(h_in + (size_t)row * FDIM + fo);
  float hd[8];
  hd[0] = __uint_as_float(ud.x << 16); hd[1] = __uint_as_float(ud.x & 0xffff0000u);
  hd[2] = __uint_as_float(ud.y << 16); hd[3] = __uint_as_float(ud.y & 0xffff0000u);
  hd[4] = __uint_as_float(ud.z << 16); hd[5] = __uint_as_float(ud.z & 0xffff0000u);
  hd[6] = __uint_as_float(ud.w << 16); hd[7] = __uint_as_float(ud.w & 0xffff0000u);
  uint4 o;
  unsigned int p0, p1;
#define PACK(k0, k1, dst_)                                        \
  { float o0 = hd[k0] + DTs * (a[k0] - hd[k0]);                   \
    float o1 = hd[k1] + DTs * (a[k1] - hd[k1]);                   \
    p0 = f2bf(o0); p1 = f2bf(o1); dst_ = p0 | (p1 << 16); }
  PACK(0, 1, o.x) PACK(2, 3, o.y) PACK(4, 5, o.z) PACK(6, 7, o.w)
#undef PACK
  *(uint4*)(h_out + (size_t)row * FDIM + fo) = o;
}

// ------------------------------ fp32 -> bf16 cast -----------------------------
__global__ __launch_bounds__(256) void cast_bf16(const float* __restrict__ srcp,
                                                 unsigned short* __restrict__ dstp, int n8) {
  int i = blockIdx.x * blockDim.x + threadIdx.x;
  if (i >= n8) return;
  const float4 v0 = *(const float4*)(srcp + (size_t)i * 8);
  const float4 v1 = *(const float4*)(srcp + (size_t)i * 8 + 4);
  ushort8 o;
  o[0] = f2bf(v0.x); o[1] = f2bf(v0.y); o[2] = f2bf(v0.z); o[3] = f2bf(v0.w);
  o[4] = f2bf(v1.x); o[5] = f2bf(v1.y); o[6] = f2bf(v1.z); o[7] = f2bf(v1.w);
  *(ushort8*)(dstp + (size_t)i * 8) = o;
}

// ------------- fused dual GEMM, LDS-staged via async global_load_lds ----------
// out = relu(Ah @ Wt^T + bias) + Ax @ Wr^T
// Tile 128x128, BK=32, 4 waves 2x2. Four unpadded 128x32 bf16 LDS tiles (32 KB).
// Staging: each wave issues 8 global_load_lds dwordx4 (16 rows x 64 B each),
// direct to LDS, no VGPR round-trip (m97 pattern). 32 MFMA per barrier pair.
__global__ __launch_bounds__(256, 2) void gemm_fused(const __bf16* __restrict__ Ah, const __bf16* __restrict__ Ax,
                                                     const __bf16* __restrict__ Wt, const __bf16* __restrict__ Wr,
                                                     const float* __restrict__ bias, float* __restrict__ out,
                                                     int M) {
  __shared__ __bf16 sA1[128 * 32];
  __shared__ __bf16 sA2[128 * 32];
  __shared__ __bf16 sB1[128 * 32];
  __shared__ __bf16 sB2[128 * 32];
  int tid = threadIdx.x;
  int wid = tid >> 6, lane = tid & 63;
  int wm = wid & 1, wn = wid >> 1;
  int lane15 = lane & 15, quad = lane >> 4;
  int m0 = blockIdx.x * 128, n0 = blockIdx.y * 128;

  // staging: wave wid covers rows [wid*32, wid*32+32) of each tile, 2 instrs of
  // 16 rows each; lane -> row chunkbase + lane/4, byte col (lane&3)*16
  int r0 = wid * 32 + (lane >> 2);
  int c0 = (lane & 3) * 8;              // element offset (8 bf16 = 16 B)
  int am0 = m0 + r0;      if (am0 >= M) am0 = M - 1;
  int am1 = m0 + r0 + 16; if (am1 >= M) am1 = M - 1;
  int bn0 = n0 + r0;                    // N dim = 512, always full tiles
  const __bf16* gA1_0 = Ah + (size_t)am0 * FDIM + c0;
  const __bf16* gA1_1 = Ah + (size_t)am1 * FDIM + c0;
  const __bf16* gA2_0 = Ax + (size_t)am0 * FDIM + c0;
  const __bf16* gA2_1 = Ax + (size_t)am1 * FDIM + c0;
  const __bf16* gB1_0 = Wt + (size_t)bn0 * FDIM + c0;
  const __bf16* gB1_1 = Wt + (size_t)(bn0 + 16) * FDIM + c0;
  const __bf16* gB2_0 = Wr + (size_t)bn0 * FDIM + c0;
  const __bf16* gB2_1 = Wr + (size_t)(bn0 + 16) * FDIM + c0;
  __bf16* lA1_0 = sA1 + (wid * 32) * 32;      __bf16* lA1_1 = lA1_0 + 16 * 32;
  __bf16* lA2_0 = sA2 + (wid * 32) * 32;      __bf16* lA2_1 = lA2_0 + 16 * 32;
  __bf16* lB1_0 = sB1 + (wid * 32) * 32;      __bf16* lB1_1 = lB1_0 + 16 * 32;
  __bf16* lB2_0 = sB2 + (wid * 32) * 32;      __bf16* lB2_1 = lB2_0 + 16 * 32;

  floatx4 acc1[4][4], acc2[4][4];
  floatx4 z4; z4[0] = 0.f; z4[1] = 0.f; z4[2] = 0.f; z4[3] = 0.f;
#pragma unroll
  for (int im = 0; im < 4; ++im)
#pragma unroll
    for (int in = 0; in < 4; ++in) { acc1[im][in] = z4; acc2[im][in] = z4; }

  for (int kt = 0; kt < FDIM; kt += 32) {
    gld16(gA1_0 + kt, lA1_0); gld16(gA1_1 + kt, lA1_1);
    gld16(gB1_0 + kt, lB1_0); gld16(gB1_1 + kt, lB1_1);
    gld16(gA2_0 + kt, lA2_0); gld16(gA2_1 + kt, lA2_1);
    gld16(gB2_0 + kt, lB2_0); gld16(gB2_1 + kt, lB2_1);
    __syncthreads();
    bf16x8 af[4], br[4];
#pragma unroll
    for (int im = 0; im < 4; ++im)
      af[im] = *(const bf16x8*)(sA1 + (wm * 64 + im * 16 + lane15) * 32 + quad * 8);
#pragma unroll
    for (int in = 0; in < 4; ++in)
      br[in] = *(const bf16x8*)(sB1 + (wn * 64 + in * 16 + lane15) * 32 + quad * 8);
#pragma unroll
    for (int im = 0; im < 4; ++im)
#pragma unroll
      for (int in = 0; in < 4; ++in)
        acc1[im][in] = __builtin_amdgcn_mfma_f32_16x16x32_bf16(af[im], br[in], acc1[im][in], 0, 0, 0);
#pragma unroll
    for (int im = 0; im < 4; ++im)
      af[im] = *(const bf16x8*)(sA2 + (wm * 64 + im * 16 + lane15) * 32 + quad * 8);
#pragma unroll
    for (int in = 0; in < 4; ++in)
      br[in] = *(const bf16x8*)(sB2 + (wn * 64 + in * 16 + lane15) * 32 + quad * 8);
#pragma unroll
    for (int im = 0; im < 4; ++im)
#pragma unroll
      for (int in = 0; in < 4; ++in)
        acc2[im][in] = __builtin_amdgcn_mfma_f32_16x16x32_bf16(af[im], br[in], acc2[im][in], 0, 0, 0);
    __syncthreads();
  }

  // epilogue: C/D layout col=lane&15, row=quad*4+reg
  float bn[4];
#pragma unroll
  for (int in = 0; in < 4; ++in) bn[in] = bias[n0 + wn * 64 + in * 16 + lane15];
#pragma unroll
  for (int im = 0; im < 4; ++im) {
#pragma unroll
    for (int in = 0; in < 4; ++in) {
#pragma unroll
      for (int r = 0; r < 4; ++r) {
        int m = m0 + wm * 64 + im * 16 + quad * 4 + r;
        int n = n0 + wn * 64 + in * 16 + lane15;
        if (m < M) {
          float v = fmaxf(acc1[im][in][r] + bn[in], 0.f) + acc2[im][in][r];
          out[(size_t)m * FDIM + n] = v;
        }
      }
    }
  }
}

// ------------------------------ rowwise LayerNorm -----------------------------
__global__ __launch_bounds__(256) void ln_kernel(const float* __restrict__ pre, const float* __restrict__ gamma,
                                                 const float* __restrict__ beta, float* __restrict__ out) {
  int row = blockIdx.x, t = threadIdx.x;
  float2 v = *(const float2*)(pre + (size_t)row * FDIM + t * 2);
  float s = v.x + v.y;
  float ss = v.x * v.x + v.y * v.y;
  for (int off = 32; off; off >>= 1) { s += __shfl_down(s, off); ss += __shfl_down(ss, off); }
  __shared__ float sm[4], sm2[4];
  int wid = t >> 6, lane = t & 63;
  if (lane == 0) { sm[wid] = s; sm2[wid] = ss; }
  __syncthreads();
  if (t == 0) {
    float a = sm[0] + sm[1] + sm[2] + sm[3];
    float b = sm2[0] + sm2[1] + sm2[2] + sm2[3];
    sm[0] = a; sm2[0] = b;
  }
  __syncthreads();
  float mu = sm[0] * (1.f / FDIM);
  float var = sm2[0] * (1.f / FDIM) - mu * mu;
  float inv = rsqrtf(var + EPSv);
  float2 g  = *(const float2*)(gamma + t * 2);
  float2 bb = *(const float2*)(beta + t * 2);
  float2 o;
  o.x = (v.x - mu) * inv * g.x + bb.x;
  o.y = (v.y - mu) * inv * g.y + bb.y;
  *(float2*)(out + (size_t)row * FDIM + t * 2) = o;
}

extern "C" void kernel_launch(void* const* d_in, const int* in_sizes, int n_in,
                              void* d_out, int out_size, void* d_ws, size_t ws_size,
                              hipStream_t stream) {
  const float* x     = (const float*)d_in[0];
  const int*   ei    = (const int*)d_in[1];
  const float* ts    = (const float*)d_in[2];
  const float* W_t   = (const float*)d_in[3];
  const float* b_t   = (const float*)d_in[4];
  const float* W_r   = (const float*)d_in[5];
  const float* gamma = (const float*)d_in[6];
  const float* beta  = (const float*)d_in[7];
  const int*   gt    = (const int*)d_in[8];

  const int E = in_sizes[2];
  const int N = in_sizes[0] / FDIM;
  const int* src = ei;
  const int* dst = ei + E;
  const int totE = E + N;

  // ---- workspace carve (all regions fully rewritten every call) ----
  char* base = (char*)d_ws;
  size_t off = 0;
  auto carve = [&](size_t bytes) -> char* {
    char* r = base + off;
    off = (off + bytes + 255) & ~(size_t)255;
    return r;
  };
  float* tsmax = (float*)carve(4);
  float* deg   = (float*)carve((size_t)N * 4);
  int*   cnt   = (int*)  carve((size_t)N * 4);
  size_t zero_bytes = off;                       // tsmax+deg+cnt need zeroing
  float* dinv  = (float*)carve((size_t)N * 4);
  int*   offs  = (int*)  carve((size_t)(N + 1) * 4);
  int*   cursor= (int*)  carve((size_t)N * 4);
  float* w     = (float*)carve((size_t)totE * 4);
  int*   col   = (int*)  carve((size_t)totE * 4);
  float* val   = (float*)carve((size_t)totE * 4);
  unsigned short* xb  = (unsigned short*)carve((size_t)N * FDIM * 2);   // bf16(x)
  unsigned short* hba = (unsigned short*)carve((size_t)N * FDIM * 2);   // bf16 h ping
  unsigned short* hbb = (unsigned short*)carve((size_t)N * FDIM * 2);   // bf16 h pong
  unsigned short* wtb = (unsigned short*)carve((size_t)FDIM * FDIM * 2);
  unsigned short* wrb = (unsigned short*)carve((size_t)FDIM * FDIM * 2);
  float* preLN = (float*)carve((size_t)N * FDIM * 4);

  hipMemsetAsync(d_ws, 0, zero_bytes, stream);

  tsmax_kernel<<<64, 256, 0, stream>>>(ts, E, tsmax);
  edge_w_deg<<<(totE + 255) / 256, 256, 0, stream>>>(src, dst, ts, tsmax, gt, w, deg, cnt, E, N);
  dinv_kernel<<<(N + 255) / 256, 256, 0, stream>>>(deg, dinv, N);
  scan_offsets<<<1, 256, 0, stream>>>(cnt, offs, cursor, N);
  scatter_kernel<<<(totE + 255) / 256, 256, 0, stream>>>(src, dst, w, dinv, cursor, col, val, E, N);

  // casts to bf16 (x and weights; x feeds both the diffusion and the residual GEMM)
  int n8x = N * FDIM / 8;
  cast_bf16<<<(n8x + 255) / 256, 256, 0, stream>>>(x, xb, n8x);
  int n8w = FDIM * FDIM / 8;
  cast_bf16<<<(n8w + 255) / 256, 256, 0, stream>>>(W_t, wtb, n8w);
  cast_bf16<<<(n8w + 255) / 256, 256, 0, stream>>>(W_r, wrb, n8w);

  // 5 Euler steps on bf16 state: xb -> hba -> hbb -> hba -> hbb -> hba
  int sg = (N + 3) / 4;
  spmm_step_bf16<<<sg, 256, 0, stream>>>(offs, col, val, xb,  hba, N);
  spmm_step_bf16<<<sg, 256, 0, stream>>>(offs, col, val, hba, hbb, N);
  spmm_step_bf16<<<sg, 256, 0, stream>>>(offs, col, val, hbb, hba, N);
  spmm_step_bf16<<<sg, 256, 0, stream>>>(offs, col, val, hba, hbb, N);
  spmm_step_bf16<<<sg, 256, 0, stream>>>(offs, col, val, hbb, hba, N);

  // fused: preLN = relu(h @ Wt^T + b_t) + x @ Wr^T
  dim3 gg((N + 127) / 128, FDIM / 128);
  gemm_fused<<<gg, 256, 0, stream>>>((const __bf16*)hba, (const __bf16*)xb,
                                     (const __bf16*)wtb, (const __bf16*)wrb,
                                     b_t, preLN, N);

  ln_kernel<<<N, 256, 0, stream>>>(preLN, gamma, beta, (float*)d_out);
}

// Round 6
// 490.937 us; speedup vs baseline: 1.2043x; 1.0532x over previous
//
#include <hip/hip_runtime.h>

// Problem constants (from reference)
#define FDIM 512
#define TDK  0.1f   // TIME_DECAY
#define DTs  0.2f   // DIFF_T / NUM_STEPS
#define EPSv 1e-5f

using bf16x8  = __attribute__((ext_vector_type(8))) __bf16;
using floatx4 = __attribute__((ext_vector_type(4))) float;
using ushort8 = __attribute__((ext_vector_type(8))) unsigned short;

__device__ __forceinline__ unsigned short f2bf(float f) {
  unsigned int u = __float_as_uint(f);
  u += 0x7fffu + ((u >> 16) & 1u);   // RNE
  return (unsigned short)(u >> 16);
}

// async global->LDS, 16 B per lane; LDS dest = wave-uniform base + lane*16
__device__ __forceinline__ void gld16(const __bf16* g, __bf16* l) {
  __builtin_amdgcn_global_load_lds(
      (const __attribute__((address_space(1))) unsigned int*)g,
      (__attribute__((address_space(3))) unsigned int*)l, 16, 0, 0);
}

// ---------------- ts.max() over timestamps (graph_time folded in later) -------
__global__ __launch_bounds__(256) void tsmax_kernel(const float* __restrict__ ts, int E,
                                                    float* __restrict__ out) {
  float m = 0.f;  // timestamps >= 0
  for (int i = blockIdx.x * blockDim.x + threadIdx.x; i < E; i += gridDim.x * blockDim.x)
    m = fmaxf(m, ts[i]);
  for (int off = 32; off; off >>= 1) m = fmaxf(m, __shfl_down(m, off));
  __shared__ float sm[4];
  int wid = threadIdx.x >> 6, lane = threadIdx.x & 63;
  if (lane == 0) sm[wid] = m;
  __syncthreads();
  if (threadIdx.x == 0) {
    float mm = fmaxf(fmaxf(sm[0], sm[1]), fmaxf(sm[2], sm[3]));
    atomicMax((int*)out, __float_as_int(mm));  // positive floats: int order == float order
  }
}

// -------- per-edge decay weight + weighted degree (dst) + CSR row counts ------
__global__ __launch_bounds__(256) void edge_w_deg(const int* __restrict__ src, const int* __restrict__ dst,
                                                  const float* __restrict__ ts, const float* __restrict__ tsmax_p,
                                                  const int* __restrict__ gt_p,
                                                  float* __restrict__ w, float* __restrict__ deg,
                                                  int* __restrict__ cnt, int E, int N) {
  int e = blockIdx.x * blockDim.x + threadIdx.x;
  int total = E + N;
  if (e >= total) return;
  float gtf = (float)(*gt_p);
  float tm = fmaxf(*tsmax_p, gtf);
  int d; float t;
  if (e < E) { d = dst[e]; t = ts[e]; }
  else       { d = e - E;  t = gtf; }
  float wv = expf(-TDK * (tm - t));
  w[e] = wv;
  atomicAdd(&deg[d], wv);
  atomicAdd(&cnt[d], 1);
}

__global__ __launch_bounds__(256) void dinv_kernel(const float* __restrict__ deg, float* __restrict__ dinv, int N) {
  int i = blockIdx.x * blockDim.x + threadIdx.x;
  if (i >= N) return;
  float d = deg[i];
  dinv[i] = (d > 0.f) ? rsqrtf(d) : 0.f;
}

// --------------- parallel 3-phase exclusive scan for CSR offsets --------------
__global__ __launch_bounds__(256) void seg_reduce(const int* __restrict__ cnt, int* __restrict__ bsum, int n) {
  int i = blockIdx.x * 256 + threadIdx.x;
  int v = (i < n) ? cnt[i] : 0;
  for (int o = 32; o; o >>= 1) v += __shfl_down(v, o);
  __shared__ int sm[4];
  if ((threadIdx.x & 63) == 0) sm[threadIdx.x >> 6] = v;
  __syncthreads();
  if (threadIdx.x == 0) bsum[blockIdx.x] = sm[0] + sm[1] + sm[2] + sm[3];
}

__global__ __launch_bounds__(256) void scan_bsum(const int* __restrict__ bsum, int* __restrict__ bbase, int nb) {
  __shared__ int sm[256];
  int t = threadIdx.x;
  int v = (t < nb) ? bsum[t] : 0;
  sm[t] = v;
  __syncthreads();
  for (int o = 1; o < 256; o <<= 1) {
    int u = (t >= o) ? sm[t - o] : 0;
    __syncthreads();
    sm[t] += u;
    __syncthreads();
  }
  if (t < nb) bbase[t] = sm[t] - v;   // exclusive
}

__global__ __launch_bounds__(256) void seg_scan(const int* __restrict__ cnt, const int* __restrict__ bbase,
                                                int* __restrict__ offs, int* __restrict__ cursor,
                                                int n, int totE) {
  __shared__ int sm[256];
  int i = blockIdx.x * 256 + threadIdx.x;
  int v = (i < n) ? cnt[i] : 0;
  sm[threadIdx.x] = v;
  __syncthreads();
  for (int o = 1; o < 256; o <<= 1) {
    int u = (threadIdx.x >= o) ? sm[threadIdx.x - o] : 0;
    __syncthreads();
    sm[threadIdx.x] += u;
    __syncthreads();
  }
  int excl = sm[threadIdx.x] - v + bbase[blockIdx.x];
  if (i < n) { offs[i] = excl; cursor[i] = excl; }
  if (i == 0) offs[n] = totE;
}

// ------ scatter edges into CSR (cv = {src, bits(dinv[src]*w*dinv[dst])}) ------
__global__ __launch_bounds__(256) void scatter_kernel(const int* __restrict__ src, const int* __restrict__ dst,
                                                      const float* __restrict__ w, const float* __restrict__ dinv,
                                                      int* __restrict__ cursor, int2* __restrict__ cv,
                                                      int E, int N) {
  int e = blockIdx.x * blockDim.x + threadIdx.x;
  if (e >= E + N) return;
  int s, d;
  if (e < E) { s = src[e]; d = dst[e]; }
  else       { s = d = e - E; }
  int pos = atomicAdd(&cursor[d], 1);
  cv[pos] = make_int2(s, __float_as_int(dinv[s] * w[e] * dinv[d]));
}

// ---- one diffusion step, bf16 state, FEATURE-CHUNKED for L2 residency -------
// chunk = 64 features (blockIdx.y, slow dispatch index): per-chunk gather
// working set = N*128 B = 2.56 MB < 4 MB per-XCD L2 -> gathers hit L2.
// 16 lanes per dst row (8 B = 4 bf16 each), 16 rows per 256-thr block.
__device__ __forceinline__ void acc4(uint2 u, float v, float* a) {
  a[0] += v * __uint_as_float(u.x << 16);
  a[1] += v * __uint_as_float(u.x & 0xffff0000u);
  a[2] += v * __uint_as_float(u.y << 16);
  a[3] += v * __uint_as_float(u.y & 0xffff0000u);
}

__global__ __launch_bounds__(256) void spmm_chunk(const int* __restrict__ offs, const int2* __restrict__ cv,
                                                  const unsigned short* __restrict__ h_in,
                                                  unsigned short* __restrict__ h_out, int N) {
  int row = blockIdx.x * 16 + (threadIdx.x >> 4);
  if (row >= N) return;
  int fo = blockIdx.y * 64 + (threadIdx.x & 15) * 4;   // 4 bf16 = 8 B per lane
  const unsigned short* hp = h_in + fo;
  int s = offs[row], e = offs[row + 1];
  float a[4] = {0.f, 0.f, 0.f, 0.f};
  int j = s;
  for (; j + 8 <= e; j += 8) {
    int2 c[8]; uint2 u[8];
#pragma unroll
    for (int t = 0; t < 8; ++t) c[t] = cv[j + t];
#pragma unroll
    for (int t = 0; t < 8; ++t) u[t] = *(const uint2*)(hp + (size_t)c[t].x * FDIM);
#pragma unroll
    for (int t = 0; t < 8; ++t) acc4(u[t], __int_as_float(c[t].y), a);
  }
  if (j + 4 <= e) {
    int2 c[4]; uint2 u[4];
#pragma unroll
    for (int t = 0; t < 4; ++t) c[t] = cv[j + t];
#pragma unroll
    for (int t = 0; t < 4; ++t) u[t] = *(const uint2*)(hp + (size_t)c[t].x * FDIM);
#pragma unroll
    for (int t = 0; t < 4; ++t) acc4(u[t], __int_as_float(c[t].y), a);
    j += 4;
  }
  for (; j < e; ++j) {
    int2 c = cv[j];
    uint2 u = *(const uint2*)(hp + (size_t)c.x * FDIM);
    acc4(u, __int_as_float(c.y), a);
  }
  // self term: h + dt*(Ah - h)
  uint2 ud = *(const uint2*)(hp + (size_t)row * FDIM);
  float hd[4];
  hd[0] = __uint_as_float(ud.x << 16); hd[1] = __uint_as_float(ud.x & 0xffff0000u);
  hd[2] = __uint_as_float(ud.y << 16); hd[3] = __uint_as_float(ud.y & 0xffff0000u);
  float o0 = hd[0] + DTs * (a[0] - hd[0]);
  float o1 = hd[1] + DTs * (a[1] - hd[1]);
  float o2 = hd[2] + DTs * (a[2] - hd[2]);
  float o3 = hd[3] + DTs * (a[3] - hd[3]);
  uint2 o;
  o.x = (unsigned int)f2bf(o0) | ((unsigned int)f2bf(o1) << 16);
  o.y = (unsigned int)f2bf(o2) | ((unsigned int)f2bf(o3) << 16);
  *(uint2*)(h_out + (size_t)row * FDIM + fo) = o;
}

// ------------------------------ fp32 -> bf16 cast -----------------------------
__global__ __launch_bounds__(256) void cast_bf16(const float* __restrict__ srcp,
                                                 unsigned short* __restrict__ dstp, int n8) {
  int i = blockIdx.x * blockDim.x + threadIdx.x;
  if (i >= n8) return;
  const float4 v0 = *(const float4*)(srcp + (size_t)i * 8);
  const float4 v1 = *(const float4*)(srcp + (size_t)i * 8 + 4);
  ushort8 o;
  o[0] = f2bf(v0.x); o[1] = f2bf(v0.y); o[2] = f2bf(v0.z); o[3] = f2bf(v0.w);
  o[4] = f2bf(v1.x); o[5] = f2bf(v1.y); o[6] = f2bf(v1.z); o[7] = f2bf(v1.w);
  *(ushort8*)(dstp + (size_t)i * 8) = o;
}

// ------------- fused dual GEMM, LDS-staged via async global_load_lds ----------
// out = relu(Ah @ Wt^T + bias) + Ax @ Wr^T
// Tile 128x128, BK=32, 4 waves 2x2, unpadded 128x32 tiles (32 KB LDS).
// K-slot SWIZZLE: LDS slot q of row r holds k-segment (q - (r>>1)) & 3, so the
// 16-lane ds_read_b128 groups tile all 32 banks 2-way (free) instead of 8-way.
// Staging lane loads the permuted 16 B segment of the same 64 B row region
// (same cache lines -> coalescing unchanged).
__global__ __launch_bounds__(256, 2) void gemm_fused(const __bf16* __restrict__ Ah, const __bf16* __restrict__ Ax,
                                                     const __bf16* __restrict__ Wt, const __bf16* __restrict__ Wr,
                                                     const float* __restrict__ bias, float* __restrict__ out,
                                                     int M) {
  __shared__ __bf16 sA1[128 * 32];
  __shared__ __bf16 sA2[128 * 32];
  __shared__ __bf16 sB1[128 * 32];
  __shared__ __bf16 sB2[128 * 32];
  int tid = threadIdx.x;
  int wid = tid >> 6, lane = tid & 63;
  int wm = wid & 1, wn = wid >> 1;
  int lane15 = lane & 15, quad = lane >> 4;
  int m0 = blockIdx.x * 128, n0 = blockIdx.y * 128;

  // staging: wave covers rows [wid*32, wid*32+32), 2 instrs of 16 rows each.
  // lane -> row wid*32 + lane/4 (+16), swizzled k-segment ((lane&3)-(lane>>3))&3
  int r0 = wid * 32 + (lane >> 2);
  int c0 = ((((lane & 3) - (lane >> 3)) & 3)) * 8;   // swizzled element offset
  int am0 = m0 + r0;      if (am0 >= M) am0 = M - 1;
  int am1 = m0 + r0 + 16; if (am1 >= M) am1 = M - 1;
  int bn0 = n0 + r0;                                 // N dim = 512, full tiles
  const __bf16* gA1_0 = Ah + (size_t)am0 * FDIM + c0;
  const __bf16* gA1_1 = Ah + (size_t)am1 * FDIM + c0;
  const __bf16* gA2_0 = Ax + (size_t)am0 * FDIM + c0;
  const __bf16* gA2_1 = Ax + (size_t)am1 * FDIM + c0;
  const __bf16* gB1_0 = Wt + (size_t)bn0 * FDIM + c0;
  const __bf16* gB1_1 = Wt + (size_t)(bn0 + 16) * FDIM + c0;
  const __bf16* gB2_0 = Wr + (size_t)bn0 * FDIM + c0;
  const __bf16* gB2_1 = Wr + (size_t)(bn0 + 16) * FDIM + c0;
  __bf16* lA1_0 = sA1 + (wid * 32) * 32;      __bf16* lA1_1 = lA1_0 + 16 * 32;
  __bf16* lA2_0 = sA2 + (wid * 32) * 32;      __bf16* lA2_1 = lA2_0 + 16 * 32;
  __bf16* lB1_0 = sB1 + (wid * 32) * 32;      __bf16* lB1_1 = lB1_0 + 16 * 32;
  __bf16* lB2_0 = sB2 + (wid * 32) * 32;      __bf16* lB2_1 = lB2_0 + 16 * 32;

  // read-side swizzled k offset: slot = (quad + (row>>1)) & 3; (row>>1)&3 =
  // (lane15>>1)&3 independent of im/wm
  int koff = ((quad + (lane15 >> 1)) & 3) * 8;

  floatx4 acc1[4][4], acc2[4][4];
  floatx4 z4; z4[0] = 0.f; z4[1] = 0.f; z4[2] = 0.f; z4[3] = 0.f;
#pragma unroll
  for (int im = 0; im < 4; ++im)
#pragma unroll
    for (int in = 0; in < 4; ++in) { acc1[im][in] = z4; acc2[im][in] = z4; }

  for (int kt = 0; kt < FDIM; kt += 32) {
    gld16(gA1_0 + kt, lA1_0); gld16(gA1_1 + kt, lA1_1);
    gld16(gB1_0 + kt, lB1_0); gld16(gB1_1 + kt, lB1_1);
    gld16(gA2_0 + kt, lA2_0); gld16(gA2_1 + kt, lA2_1);
    gld16(gB2_0 + kt, lB2_0); gld16(gB2_1 + kt, lB2_1);
    __syncthreads();
    bf16x8 af[4], br[4];
#pragma unroll
    for (int im = 0; im < 4; ++im)
      af[im] = *(const bf16x8*)(sA1 + (wm * 64 + im * 16 + lane15) * 32 + koff);
#pragma unroll
    for (int in = 0; in < 4; ++in)
      br[in] = *(const bf16x8*)(sB1 + (wn * 64 + in * 16 + lane15) * 32 + koff);
#pragma unroll
    for (int im = 0; im < 4; ++im)
#pragma unroll
      for (int in = 0; in < 4; ++in)
        acc1[im][in] = __builtin_amdgcn_mfma_f32_16x16x32_bf16(af[im], br[in], acc1[im][in], 0, 0, 0);
#pragma unroll
    for (int im = 0; im < 4; ++im)
      af[im] = *(const bf16x8*)(sA2 + (wm * 64 + im * 16 + lane15) * 32 + koff);
#pragma unroll
    for (int in = 0; in < 4; ++in)
      br[in] = *(const bf16x8*)(sB2 + (wn * 64 + in * 16 + lane15) * 32 + koff);
#pragma unroll
    for (int im = 0; im < 4; ++im)
#pragma unroll
      for (int in = 0; in < 4; ++in)
        acc2[im][in] = __builtin_amdgcn_mfma_f32_16x16x32_bf16(af[im], br[in], acc2[im][in], 0, 0, 0);
    __syncthreads();
  }

  // epilogue: C/D layout col=lane&15, row=quad*4+reg
  float bn[4];
#pragma unroll
  for (int in = 0; in < 4; ++in) bn[in] = bias[n0 + wn * 64 + in * 16 + lane15];
#pragma unroll
  for (int im = 0; im < 4; ++im) {
#pragma unroll
    for (int in = 0; in < 4; ++in) {
#pragma unroll
      for (int r = 0; r < 4; ++r) {
        int m = m0 + wm * 64 + im * 16 + quad * 4 + r;
        int n = n0 + wn * 64 + in * 16 + lane15;
        if (m < M) {
          float v = fmaxf(acc1[im][in][r] + bn[in], 0.f) + acc2[im][in][r];
          out[(size_t)m * FDIM + n] = v;
        }
      }
    }
  }
}

// ------------------------------ rowwise LayerNorm -----------------------------
__global__ __launch_bounds__(256) void ln_kernel(const float* __restrict__ pre, const float* __restrict__ gamma,
                                                 const float* __restrict__ beta, float* __restrict__ out) {
  int row = blockIdx.x, t = threadIdx.x;
  float2 v = *(const float2*)(pre + (size_t)row * FDIM + t * 2);
  float s = v.x + v.y;
  float ss = v.x * v.x + v.y * v.y;
  for (int off = 32; off; off >>= 1) { s += __shfl_down(s, off); ss += __shfl_down(ss, off); }
  __shared__ float sm[4], sm2[4];
  int wid = t >> 6, lane = t & 63;
  if (lane == 0) { sm[wid] = s; sm2[wid] = ss; }
  __syncthreads();
  if (t == 0) {
    float a = sm[0] + sm[1] + sm[2] + sm[3];
    float b = sm2[0] + sm2[1] + sm2[2] + sm2[3];
    sm[0] = a; sm2[0] = b;
  }
  __syncthreads();
  float mu = sm[0] * (1.f / FDIM);
  float var = sm2[0] * (1.f / FDIM) - mu * mu;
  float inv = rsqrtf(var + EPSv);
  float2 g  = *(const float2*)(gamma + t * 2);
  float2 bb = *(const float2*)(beta + t * 2);
  float2 o;
  o.x = (v.x - mu) * inv * g.x + bb.x;
  o.y = (v.y - mu) * inv * g.y + bb.y;
  *(float2*)(out + (size_t)row * FDIM + t * 2) = o;
}

extern "C" void kernel_launch(void* const* d_in, const int* in_sizes, int n_in,
                              void* d_out, int out_size, void* d_ws, size_t ws_size,
                              hipStream_t stream) {
  const float* x     = (const float*)d_in[0];
  const int*   ei    = (const int*)d_in[1];
  const float* ts    = (const float*)d_in[2];
  const float* W_t   = (const float*)d_in[3];
  const float* b_t   = (const float*)d_in[4];
  const float* W_r   = (const float*)d_in[5];
  const float* gamma = (const float*)d_in[6];
  const float* beta  = (const float*)d_in[7];
  const int*   gt    = (const int*)d_in[8];

  const int E = in_sizes[2];
  const int N = in_sizes[0] / FDIM;
  const int* src = ei;
  const int* dst = ei + E;
  const int totE = E + N;
  const int nb = (N + 255) / 256;   // scan segments (<=256 assumed; N=20000 -> 79)

  // ---- workspace carve (all regions fully rewritten every call) ----
  char* base = (char*)d_ws;
  size_t off = 0;
  auto carve = [&](size_t bytes) -> char* {
    char* r = base + off;
    off = (off + bytes + 255) & ~(size_t)255;
    return r;
  };
  float* tsmax = (float*)carve(4);
  float* deg   = (float*)carve((size_t)N * 4);
  int*   cnt   = (int*)  carve((size_t)N * 4);
  size_t zero_bytes = off;                       // tsmax+deg+cnt need zeroing
  float* dinv  = (float*)carve((size_t)N * 4);
  int*   offs  = (int*)  carve((size_t)(N + 1) * 4);
  int*   cursor= (int*)  carve((size_t)N * 4);
  int*   bsum  = (int*)  carve((size_t)nb * 4);
  int*   bbase = (int*)  carve((size_t)nb * 4);
  float* w     = (float*)carve((size_t)totE * 4);
  int2*  cv    = (int2*) carve((size_t)totE * 8);
  unsigned short* xb  = (unsigned short*)carve((size_t)N * FDIM * 2);   // bf16(x)
  unsigned short* hba = (unsigned short*)carve((size_t)N * FDIM * 2);   // bf16 h ping
  unsigned short* hbb = (unsigned short*)carve((size_t)N * FDIM * 2);   // bf16 h pong
  unsigned short* wtb = (unsigned short*)carve((size_t)FDIM * FDIM * 2);
  unsigned short* wrb = (unsigned short*)carve((size_t)FDIM * FDIM * 2);
  float* preLN = (float*)carve((size_t)N * FDIM * 4);

  hipMemsetAsync(d_ws, 0, zero_bytes, stream);

  tsmax_kernel<<<64, 256, 0, stream>>>(ts, E, tsmax);
  edge_w_deg<<<(totE + 255) / 256, 256, 0, stream>>>(src, dst, ts, tsmax, gt, w, deg, cnt, E, N);
  dinv_kernel<<<(N + 255) / 256, 256, 0, stream>>>(deg, dinv, N);
  seg_reduce<<<nb, 256, 0, stream>>>(cnt, bsum, N);
  scan_bsum<<<1, 256, 0, stream>>>(bsum, bbase, nb);
  seg_scan<<<nb, 256, 0, stream>>>(cnt, bbase, offs, cursor, N, totE);
  scatter_kernel<<<(totE + 255) / 256, 256, 0, stream>>>(src, dst, w, dinv, cursor, cv, E, N);

  // casts to bf16 (x and weights; x feeds both the diffusion and the residual GEMM)
  int n8x = N * FDIM / 8;
  cast_bf16<<<(n8x + 255) / 256, 256, 0, stream>>>(x, xb, n8x);
  int n8w = FDIM * FDIM / 8;
  cast_bf16<<<(n8w + 255) / 256, 256, 0, stream>>>(W_t, wtb, n8w);
  cast_bf16<<<(n8w + 255) / 256, 256, 0, stream>>>(W_r, wrb, n8w);

  // 5 Euler steps on bf16 state, feature-chunked (8 chunks of 64 feats)
  dim3 sgrid((N + 15) / 16, FDIM / 64);
  spmm_chunk<<<sgrid, 256, 0, stream>>>(offs, cv, xb,  hba, N);
  spmm_chunk<<<sgrid, 256, 0, stream>>>(offs, cv, hba, hbb, N);
  spmm_chunk<<<sgrid, 256, 0, stream>>>(offs, cv, hbb, hba, N);
  spmm_chunk<<<sgrid, 256, 0, stream>>>(offs, cv, hba, hbb, N);
  spmm_chunk<<<sgrid, 256, 0, stream>>>(offs, cv, hbb, hba, N);

  // fused: preLN = relu(h @ Wt^T + b_t) + x @ Wr^T
  dim3 gg((N + 127) / 128, FDIM / 128);
  gemm_fused<<<gg, 256, 0, stream>>>((const __bf16*)hba, (const __bf16*)xb,
                                     (const __bf16*)wtb, (const __bf16*)wrb,
                                     b_t, preLN, N);

  ln_kernel<<<N, 256, 0, stream>>>(preLN, gamma, beta, (float*)d_out);
}

// Round 8
// 402.114 us; speedup vs baseline: 1.4703x; 1.2209x over previous
//
#include <hip/hip_runtime.h>
#include <hip/hip_fp16.h>

// Problem constants (from reference)
#define FDIM 512
#define TDK  0.1f   // TIME_DECAY
#define DTs  0.2f   // DIFF_T / NUM_STEPS
#define EPSv 1e-5f

using bf16x8  = __attribute__((ext_vector_type(8))) __bf16;
using floatx4 = __attribute__((ext_vector_type(4))) float;
using ushort8 = __attribute__((ext_vector_type(8))) unsigned short;
using uintx4  = __attribute__((ext_vector_type(4))) unsigned int;   // native vec for nontemporal builtins

__device__ __forceinline__ unsigned short f2bf(float f) {
  unsigned int u = __float_as_uint(f);
  u += 0x7fffu + ((u >> 16) & 1u);   // RNE
  return (unsigned short)(u >> 16);
}

// async global->LDS, 16 B per lane; LDS dest = wave-uniform base + lane*16
__device__ __forceinline__ void gld16(const __bf16* g, __bf16* l) {
  __builtin_amdgcn_global_load_lds(
      (const __attribute__((address_space(1))) unsigned int*)g,
      (__attribute__((address_space(3))) unsigned int*)l, 16, 0, 0);
}

// ---------------- ts.max() over timestamps (graph_time folded in later) -------
__global__ __launch_bounds__(256) void tsmax_kernel(const float* __restrict__ ts, int E,
                                                    float* __restrict__ out) {
  float m = 0.f;  // timestamps >= 0
  for (int i = blockIdx.x * blockDim.x + threadIdx.x; i < E; i += gridDim.x * blockDim.x)
    m = fmaxf(m, ts[i]);
  for (int off = 32; off; off >>= 1) m = fmaxf(m, __shfl_down(m, off));
  __shared__ float sm[4];
  int wid = threadIdx.x >> 6, lane = threadIdx.x & 63;
  if (lane == 0) sm[wid] = m;
  __syncthreads();
  if (threadIdx.x == 0) {
    float mm = fmaxf(fmaxf(sm[0], sm[1]), fmaxf(sm[2], sm[3]));
    atomicMax((int*)out, __float_as_int(mm));  // positive floats: int order == float order
  }
}

// -------- per-edge decay weight + weighted degree (dst) + CSR row counts ------
__global__ __launch_bounds__(256) void edge_w_deg(const int* __restrict__ src, const int* __restrict__ dst,
                                                  const float* __restrict__ ts, const float* __restrict__ tsmax_p,
                                                  const int* __restrict__ gt_p,
                                                  float* __restrict__ w, float* __restrict__ deg,
                                                  int* __restrict__ cnt, int E, int N) {
  int e = blockIdx.x * blockDim.x + threadIdx.x;
  int total = E + N;
  if (e >= total) return;
  float gtf = (float)(*gt_p);
  float tm = fmaxf(*tsmax_p, gtf);
  int d; float t;
  if (e < E) { d = dst[e]; t = ts[e]; }
  else       { d = e - E;  t = gtf; }
  float wv = expf(-TDK * (tm - t));
  w[e] = wv;
  atomicAdd(&deg[d], wv);
  atomicAdd(&cnt[d], 1);
}

__global__ __launch_bounds__(256) void dinv_kernel(const float* __restrict__ deg, float* __restrict__ dinv, int N) {
  int i = blockIdx.x * blockDim.x + threadIdx.x;
  if (i >= N) return;
  float d = deg[i];
  dinv[i] = (d > 0.f) ? rsqrtf(d) : 0.f;
}

// --------------- parallel 3-phase exclusive scan for CSR offsets --------------
__global__ __launch_bounds__(256) void seg_reduce(const int* __restrict__ cnt, int* __restrict__ bsum, int n) {
  int i = blockIdx.x * 256 + threadIdx.x;
  int v = (i < n) ? cnt[i] : 0;
  for (int o = 32; o; o >>= 1) v += __shfl_down(v, o);
  __shared__ int sm[4];
  if ((threadIdx.x & 63) == 0) sm[threadIdx.x >> 6] = v;
  __syncthreads();
  if (threadIdx.x == 0) bsum[blockIdx.x] = sm[0] + sm[1] + sm[2] + sm[3];
}

__global__ __launch_bounds__(256) void scan_bsum(const int* __restrict__ bsum, int* __restrict__ bbase, int nb) {
  __shared__ int sm[256];
  int t = threadIdx.x;
  int v = (t < nb) ? bsum[t] : 0;
  sm[t] = v;
  __syncthreads();
  for (int o = 1; o < 256; o <<= 1) {
    int u = (t >= o) ? sm[t - o] : 0;
    __syncthreads();
    sm[t] += u;
    __syncthreads();
  }
  if (t < nb) bbase[t] = sm[t] - v;   // exclusive
}

__global__ __launch_bounds__(256) void seg_scan(const int* __restrict__ cnt, const int* __restrict__ bbase,
                                                int* __restrict__ offs, int* __restrict__ cursor,
                                                int n, int totE) {
  __shared__ int sm[256];
  int i = blockIdx.x * 256 + threadIdx.x;
  int v = (i < n) ? cnt[i] : 0;
  sm[threadIdx.x] = v;
  __syncthreads();
  for (int o = 1; o < 256; o <<= 1) {
    int u = (threadIdx.x >= o) ? sm[threadIdx.x - o] : 0;
    __syncthreads();
    sm[threadIdx.x] += u;
    __syncthreads();
  }
  int excl = sm[threadIdx.x] - v + bbase[blockIdx.x];
  if (i < n) { offs[i] = excl; cursor[i] = excl; }
  if (i == 0) offs[n] = totE;
}

// -- scatter edges into CSR, packed 4 B: lo16 = src (N<65536), hi16 = fp16 val -
__global__ __launch_bounds__(256) void scatter_kernel(const int* __restrict__ src, const int* __restrict__ dst,
                                                      const float* __restrict__ w, const float* __restrict__ dinv,
                                                      int* __restrict__ cursor, unsigned* __restrict__ cv,
                                                      int E, int N) {
  int e = blockIdx.x * blockDim.x + threadIdx.x;
  if (e >= E + N) return;
  int s, d;
  if (e < E) { s = src[e]; d = dst[e]; }
  else       { s = d = e - E; }
  int pos = atomicAdd(&cursor[d], 1);
  float v = dinv[s] * w[e] * dinv[d];
  unsigned short hv = __half_as_ushort(__float2half(v));
  cv[pos] = (unsigned)s | ((unsigned)hv << 16);
}

// ---- one diffusion step, bf16 state, XCD-AFFINE feature chunks --------------
// chunk = blockIdx.x & 7 (fast index): round-robin dispatch puts all of chunk c
// on one XCD, whose 4 MB L2 then holds the whole 2.56 MB gather slab (+1.36 MB
// cv). h_out is nontemporal-stored so writes don't evict the read slab.
// 8 lanes/row x 16 B (uintx4 = full 128 B line per edge), 32 rows per block.
__device__ __forceinline__ void acc8(uintx4 u, float v, float* a) {
  a[0] += v * __uint_as_float(u[0] << 16);
  a[1] += v * __uint_as_float(u[0] & 0xffff0000u);
  a[2] += v * __uint_as_float(u[1] << 16);
  a[3] += v * __uint_as_float(u[1] & 0xffff0000u);
  a[4] += v * __uint_as_float(u[2] << 16);
  a[5] += v * __uint_as_float(u[2] & 0xffff0000u);
  a[6] += v * __uint_as_float(u[3] << 16);
  a[7] += v * __uint_as_float(u[3] & 0xffff0000u);
}

__device__ __forceinline__ float cvval(unsigned cu) {
  return __half2float(__ushort_as_half((unsigned short)(cu >> 16)));
}

__global__ __launch_bounds__(256) void spmm_xcd(const int* __restrict__ offs, const unsigned* __restrict__ cv,
                                                const unsigned short* __restrict__ h_in,
                                                unsigned short* __restrict__ h_out, int N) {
  int chunk = blockIdx.x & 7;
  int tile  = blockIdx.x >> 3;
  int row = tile * 32 + (threadIdx.x >> 3);
  if (row >= N) return;
  int fo = chunk * 64 + (threadIdx.x & 7) * 8;   // 8 bf16 = 16 B per lane
  const unsigned short* hp = h_in + fo;
  int s = offs[row], e = offs[row + 1];
  float a[8] = {0.f, 0.f, 0.f, 0.f, 0.f, 0.f, 0.f, 0.f};
  int j = s;
  for (; j + 8 <= e; j += 8) {
    unsigned cu[8]; uintx4 u[8];
#pragma unroll
    for (int t = 0; t < 8; ++t) cu[t] = cv[j + t];
#pragma unroll
    for (int t = 0; t < 8; ++t) u[t] = *(const uintx4*)(hp + ((cu[t] & 0xffffu) << 9));
#pragma unroll
    for (int t = 0; t < 8; ++t) acc8(u[t], cvval(cu[t]), a);
  }
  if (j + 4 <= e) {
    unsigned cu[4]; uintx4 u[4];
#pragma unroll
    for (int t = 0; t < 4; ++t) cu[t] = cv[j + t];
#pragma unroll
    for (int t = 0; t < 4; ++t) u[t] = *(const uintx4*)(hp + ((cu[t] & 0xffffu) << 9));
#pragma unroll
    for (int t = 0; t < 4; ++t) acc8(u[t], cvval(cu[t]), a);
    j += 4;
  }
  for (; j < e; ++j) {
    unsigned cu = cv[j];
    uintx4 u = *(const uintx4*)(hp + ((cu & 0xffffu) << 9));
    acc8(u, cvval(cu), a);
  }
  // self term: h + dt*(Ah - h)
  uintx4 ud = *(const uintx4*)(hp + (row << 9));
  float hd[8];
  hd[0] = __uint_as_float(ud[0] << 16); hd[1] = __uint_as_float(ud[0] & 0xffff0000u);
  hd[2] = __uint_as_float(ud[1] << 16); hd[3] = __uint_as_float(ud[1] & 0xffff0000u);
  hd[4] = __uint_as_float(ud[2] << 16); hd[5] = __uint_as_float(ud[2] & 0xffff0000u);
  hd[6] = __uint_as_float(ud[3] << 16); hd[7] = __uint_as_float(ud[3] & 0xffff0000u);
  uintx4 o;
  unsigned int p0, p1;
#define PACK(k0, k1, dst_)                                        \
  { float o0 = hd[k0] + DTs * (a[k0] - hd[k0]);                   \
    float o1 = hd[k1] + DTs * (a[k1] - hd[k1]);                   \
    p0 = f2bf(o0); p1 = f2bf(o1); dst_ = p0 | (p1 << 16); }
  PACK(0, 1, o[0]) PACK(2, 3, o[1]) PACK(4, 5, o[2]) PACK(6, 7, o[3])
#undef PACK
  __builtin_nontemporal_store(o, (uintx4*)(h_out + (size_t)row * FDIM + fo));
}

// ------------------------------ fp32 -> bf16 cast -----------------------------
__global__ __launch_bounds__(256) void cast_bf16(const float* __restrict__ srcp,
                                                 unsigned short* __restrict__ dstp, int n8) {
  int i = blockIdx.x * blockDim.x + threadIdx.x;
  if (i >= n8) return;
  const float4 v0 = *(const float4*)(srcp + (size_t)i * 8);
  const float4 v1 = *(const float4*)(srcp + (size_t)i * 8 + 4);
  ushort8 o;
  o[0] = f2bf(v0.x); o[1] = f2bf(v0.y); o[2] = f2bf(v0.z); o[3] = f2bf(v0.w);
  o[4] = f2bf(v1.x); o[5] = f2bf(v1.y); o[6] = f2bf(v1.z); o[7] = f2bf(v1.w);
  *(ushort8*)(dstp + (size_t)i * 8) = o;
}

// --- fused dual GEMM, double-buffered async-LDS staging (one barrier/iter) ----
// out = relu(Ah @ Wt^T + bias) + Ax @ Wr^T
// Tile 128x128, BK=32, 4 waves 2x2, 2 x (4 x 8 KB) LDS buffers = 64 KB.
// Per iter: barrier -> prefetch tile k+1 into other buffer (async gld16) ->
// ds_read + 32 MFMA on tile k. Barrier vmcnt(0) drain only pays the staging
// latency residual beyond compute. K-slot swizzle keeps bank conflicts at 0.
__global__ __launch_bounds__(256, 2) void gemm_fused(const __bf16* __restrict__ Ah, const __bf16* __restrict__ Ax,
                                                     const __bf16* __restrict__ Wt, const __bf16* __restrict__ Wr,
                                                     const float* __restrict__ bias, float* __restrict__ out,
                                                     int M) {
  __shared__ __bf16 sA1[2][128 * 32];
  __shared__ __bf16 sA2[2][128 * 32];
  __shared__ __bf16 sB1[2][128 * 32];
  __shared__ __bf16 sB2[2][128 * 32];
  int tid = threadIdx.x;
  int wid = tid >> 6, lane = tid & 63;
  int wm = wid & 1, wn = wid >> 1;
  int lane15 = lane & 15, quad = lane >> 4;
  int m0 = blockIdx.x * 128, n0 = blockIdx.y * 128;

  // staging: wave covers rows [wid*32, wid*32+32), 2 instrs of 16 rows each.
  // lane -> row wid*32 + lane/4 (+16), swizzled k-segment ((lane&3)-(lane>>3))&3
  int r0 = wid * 32 + (lane >> 2);
  int c0 = ((((lane & 3) - (lane >> 3)) & 3)) * 8;   // swizzled element offset
  int am0 = m0 + r0;      if (am0 >= M) am0 = M - 1;
  int am1 = m0 + r0 + 16; if (am1 >= M) am1 = M - 1;
  int bn0 = n0 + r0;                                 // N dim = 512, full tiles
  const __bf16* gA1_0 = Ah + (size_t)am0 * FDIM + c0;
  const __bf16* gA1_1 = Ah + (size_t)am1 * FDIM + c0;
  const __bf16* gA2_0 = Ax + (size_t)am0 * FDIM + c0;
  const __bf16* gA2_1 = Ax + (size_t)am1 * FDIM + c0;
  const __bf16* gB1_0 = Wt + (size_t)bn0 * FDIM + c0;
  const __bf16* gB1_1 = Wt + (size_t)(bn0 + 16) * FDIM + c0;
  const __bf16* gB2_0 = Wr + (size_t)bn0 * FDIM + c0;
  const __bf16* gB2_1 = Wr + (size_t)(bn0 + 16) * FDIM + c0;
  int loff0 = wid * 1024;          // (wid*32 rows) * 32 elems
  int loff1 = wid * 1024 + 512;    // +16 rows

  auto stage = [&](int b, int kt) {
    gld16(gA1_0 + kt, &sA1[b][loff0]); gld16(gA1_1 + kt, &sA1[b][loff1]);
    gld16(gB1_0 + kt, &sB1[b][loff0]); gld16(gB1_1 + kt, &sB1[b][loff1]);
    gld16(gA2_0 + kt, &sA2[b][loff0]); gld16(gA2_1 + kt, &sA2[b][loff1]);
    gld16(gB2_0 + kt, &sB2[b][loff0]); gld16(gB2_1 + kt, &sB2[b][loff1]);
  };

  // read-side swizzled k offset: slot = (quad + (row>>1)) & 3
  int koff = ((quad + (lane15 >> 1)) & 3) * 8;

  floatx4 acc1[4][4], acc2[4][4];
  floatx4 z4; z4[0] = 0.f; z4[1] = 0.f; z4[2] = 0.f; z4[3] = 0.f;
#pragma unroll
  for (int im = 0; im < 4; ++im)
#pragma unroll
    for (int in = 0; in < 4; ++in) { acc1[im][in] = z4; acc2[im][in] = z4; }

  stage(0, 0);
  for (int it = 0; it < 16; ++it) {
    int cb = it & 1;
    __syncthreads();                       // staging of buf cb complete; prior reads of buf 1-cb done
    if (it + 1 < 16) stage(1 - cb, (it + 1) * 32);
    bf16x8 af[4], br[4];
#pragma unroll
    for (int im = 0; im < 4; ++im)
      af[im] = *(const bf16x8*)(&sA1[cb][(wm * 64 + im * 16 + lane15) * 32 + koff]);
#pragma unroll
    for (int in = 0; in < 4; ++in)
      br[in] = *(const bf16x8*)(&sB1[cb][(wn * 64 + in * 16 + lane15) * 32 + koff]);
#pragma unroll
    for (int im = 0; im < 4; ++im)
#pragma unroll
      for (int in = 0; in < 4; ++in)
        acc1[im][in] = __builtin_amdgcn_mfma_f32_16x16x32_bf16(af[im], br[in], acc1[im][in], 0, 0, 0);
#pragma unroll
    for (int im = 0; im < 4; ++im)
      af[im] = *(const bf16x8*)(&sA2[cb][(wm * 64 + im * 16 + lane15) * 32 + koff]);
#pragma unroll
    for (int in = 0; in < 4; ++in)
      br[in] = *(const bf16x8*)(&sB2[cb][(wn * 64 + in * 16 + lane15) * 32 + koff]);
#pragma unroll
    for (int im = 0; im < 4; ++im)
#pragma unroll
      for (int in = 0; in < 4; ++in)
        acc2[im][in] = __builtin_amdgcn_mfma_f32_16x16x32_bf16(af[im], br[in], acc2[im][in], 0, 0, 0);
  }

  // epilogue: C/D layout col=lane&15, row=quad*4+reg
  float bn[4];
#pragma unroll
  for (int in = 0; in < 4; ++in) bn[in] = bias[n0 + wn * 64 + in * 16 + lane15];
#pragma unroll
  for (int im = 0; im < 4; ++im) {
#pragma unroll
    for (int in = 0; in < 4; ++in) {
#pragma unroll
      for (int r = 0; r < 4; ++r) {
        int m = m0 + wm * 64 + im * 16 + quad * 4 + r;
        int n = n0 + wn * 64 + in * 16 + lane15;
        if (m < M) {
          float v = fmaxf(acc1[im][in][r] + bn[in], 0.f) + acc2[im][in][r];
          out[(size_t)m * FDIM + n] = v;
        }
      }
    }
  }
}

// ------------------------------ rowwise LayerNorm -----------------------------
__global__ __launch_bounds__(256) void ln_kernel(const float* __restrict__ pre, const float* __restrict__ gamma,
                                                 const float* __restrict__ beta, float* __restrict__ out) {
  int row = blockIdx.x, t = threadIdx.x;
  float2 v = *(const float2*)(pre + (size_t)row * FDIM + t * 2);
  float s = v.x + v.y;
  float ss = v.x * v.x + v.y * v.y;
  for (int off = 32; off; off >>= 1) { s += __shfl_down(s, off); ss += __shfl_down(ss, off); }
  __shared__ float sm[4], sm2[4];
  int wid = t >> 6, lane = t & 63;
  if (lane == 0) { sm[wid] = s; sm2[wid] = ss; }
  __syncthreads();
  if (t == 0) {
    float a = sm[0] + sm[1] + sm[2] + sm[3];
    float b = sm2[0] + sm2[1] + sm2[2] + sm2[3];
    sm[0] = a; sm2[0] = b;
  }
  __syncthreads();
  float mu = sm[0] * (1.f / FDIM);
  float var = sm2[0] * (1.f / FDIM) - mu * mu;
  float inv = rsqrtf(var + EPSv);
  float2 g  = *(const float2*)(gamma + t * 2);
  float2 bb = *(const float2*)(beta + t * 2);
  float2 o;
  o.x = (v.x - mu) * inv * g.x + bb.x;
  o.y = (v.y - mu) * inv * g.y + bb.y;
  *(float2*)(out + (size_t)row * FDIM + t * 2) = o;
}

extern "C" void kernel_launch(void* const* d_in, const int* in_sizes, int n_in,
                              void* d_out, int out_size, void* d_ws, size_t ws_size,
                              hipStream_t stream) {
  const float* x     = (const float*)d_in[0];
  const int*   ei    = (const int*)d_in[1];
  const float* ts    = (const float*)d_in[2];
  const float* W_t   = (const float*)d_in[3];
  const float* b_t   = (const float*)d_in[4];
  const float* W_r   = (const float*)d_in[5];
  const float* gamma = (const float*)d_in[6];
  const float* beta  = (const float*)d_in[7];
  const int*   gt    = (const int*)d_in[8];

  const int E = in_sizes[2];
  const int N = in_sizes[0] / FDIM;
  const int* src = ei;
  const int* dst = ei + E;
  const int totE = E + N;
  const int nb = (N + 255) / 256;   // scan segments (N=20000 -> 79 <= 256)

  // ---- workspace carve (all regions fully rewritten every call) ----
  char* base = (char*)d_ws;
  size_t off = 0;
  auto carve = [&](size_t bytes) -> char* {
    char* r = base + off;
    off = (off + bytes + 255) & ~(size_t)255;
    return r;
  };
  float* tsmax = (float*)carve(4);
  float* deg   = (float*)carve((size_t)N * 4);
  int*   cnt   = (int*)  carve((size_t)N * 4);
  size_t zero_bytes = off;                       // tsmax+deg+cnt need zeroing
  float* dinv  = (float*)carve((size_t)N * 4);
  int*   offs  = (int*)  carve((size_t)(N + 1) * 4);
  int*   cursor= (int*)  carve((size_t)N * 4);
  int*   bsum  = (int*)  carve((size_t)nb * 4);
  int*   bbase = (int*)  carve((size_t)nb * 4);
  float* w     = (float*)carve((size_t)totE * 4);
  unsigned* cv = (unsigned*)carve((size_t)totE * 4);
  unsigned short* xb  = (unsigned short*)carve((size_t)N * FDIM * 2);   // bf16(x)
  unsigned short* hba = (unsigned short*)carve((size_t)N * FDIM * 2);   // bf16 h ping
  unsigned short* hbb = (unsigned short*)carve((size_t)N * FDIM * 2);   // bf16 h pong
  unsigned short* wtb = (unsigned short*)carve((size_t)FDIM * FDIM * 2);
  unsigned short* wrb = (unsigned short*)carve((size_t)FDIM * FDIM * 2);
  float* preLN = (float*)carve((size_t)N * FDIM * 4);

  hipMemsetAsync(d_ws, 0, zero_bytes, stream);

  tsmax_kernel<<<64, 256, 0, stream>>>(ts, E, tsmax);
  edge_w_deg<<<(totE + 255) / 256, 256, 0, stream>>>(src, dst, ts, tsmax, gt, w, deg, cnt, E, N);
  dinv_kernel<<<(N + 255) / 256, 256, 0, stream>>>(deg, dinv, N);
  seg_reduce<<<nb, 256, 0, stream>>>(cnt, bsum, N);
  scan_bsum<<<1, 256, 0, stream>>>(bsum, bbase, nb);
  seg_scan<<<nb, 256, 0, stream>>>(cnt, bbase, offs, cursor, N, totE);
  scatter_kernel<<<(totE + 255) / 256, 256, 0, stream>>>(src, dst, w, dinv, cursor, cv, E, N);

  // casts to bf16 (x and weights; x feeds both the diffusion and the residual GEMM)
  int n8x = N * FDIM / 8;
  cast_bf16<<<(n8x + 255) / 256, 256, 0, stream>>>(x, xb, n8x);
  int n8w = FDIM * FDIM / 8;
  cast_bf16<<<(n8w + 255) / 256, 256, 0, stream>>>(W_t, wtb, n8w);
  cast_bf16<<<(n8w + 255) / 256, 256, 0, stream>>>(W_r, wrb, n8w);

  // 5 Euler steps on bf16 state; chunk = blockIdx&7 -> XCD-affine L2 residency
  int sgrid = ((N + 31) / 32) * 8;
  spmm_xcd<<<sgrid, 256, 0, stream>>>(offs, cv, xb,  hba, N);
  spmm_xcd<<<sgrid, 256, 0, stream>>>(offs, cv, hba, hbb, N);
  spmm_xcd<<<sgrid, 256, 0, stream>>>(offs, cv, hbb, hba, N);
  spmm_xcd<<<sgrid, 256, 0, stream>>>(offs, cv, hba, hbb, N);
  spmm_xcd<<<sgrid, 256, 0, stream>>>(offs, cv, hbb, hba, N);

  // fused: preLN = relu(h @ Wt^T + b_t) + x @ Wr^T
  dim3 gg((N + 127) / 128, FDIM / 128);
  gemm_fused<<<gg, 256, 0, stream>>>((const __bf16*)hba, (const __bf16*)xb,
                                     (const __bf16*)wtb, (const __bf16*)wrb,
                                     b_t, preLN, N);

  ln_kernel<<<N, 256, 0, stream>>>(preLN, gamma, beta, (float*)d_out);
}